// Round 5
// baseline (535.512 us; speedup 1.0000x reference)
//
#include <hip/hip_runtime.h>
#include <hip/hip_bf16.h>

#define B_ROWS   4096
#define L_LABELS 100000
#define L_PAD    100032   // 6252*16: slack rows so depth-1 prefetch stays in-bounds
#define D_DIM    256
#define TOPK     5
#define NSTEP    6250     // 100000 / 16 exact -> no pad corrections
#define NSTRIP   64       // label strips (16 groups x 2 z x 2 sp)

typedef __bf16 bf16x8 __attribute__((ext_vector_type(8)));
typedef __bf16 bf16x4 __attribute__((ext_vector_type(4)));
typedef float  f32x4  __attribute__((ext_vector_type(4)));

// ---------------------------------------------------------------------------
// fp32 -> bf16 converters
// ---------------------------------------------------------------------------
__global__ void convertP_kernel(const float* __restrict__ src,
                                __hip_bfloat16* __restrict__ dst) {
    size_t i = ((size_t)blockIdx.x * blockDim.x + threadIdx.x) * 8;
    float4 a = *(const float4*)(src + i);
    float4 b = *(const float4*)(src + i + 4);
    bf16x8 v = {(__bf16)a.x, (__bf16)a.y, (__bf16)a.z, (__bf16)a.w,
                (__bf16)b.x, (__bf16)b.y, (__bf16)b.z, (__bf16)b.w};
    *(bf16x8*)((__bf16*)dst + i) = v;
}

__global__ void convertL_kernel(const float* __restrict__ src,
                                __hip_bfloat16* __restrict__ dst) {
    size_t i = ((size_t)blockIdx.x * blockDim.x + threadIdx.x) * 8;
    bf16x8 v;
    if (i < (size_t)L_LABELS * D_DIM) {
        float4 a = *(const float4*)(src + i);
        float4 b = *(const float4*)(src + i + 4);
        v = (bf16x8){(__bf16)a.x, (__bf16)a.y, (__bf16)a.z, (__bf16)a.w,
                     (__bf16)b.x, (__bf16)b.y, (__bf16)b.z, (__bf16)b.w};
    } else {
        v = (bf16x8){(__bf16)0.f, (__bf16)0.f, (__bf16)0.f, (__bf16)0.f,
                     (__bf16)0.f, (__bf16)0.f, (__bf16)0.f, (__bf16)0.f};
    }
    *(bf16x8*)((__bf16*)dst + i) = v;
}

// ---------------------------------------------------------------------------
// Kernel 1: per-row threshold s_t (bf16-rounded inputs) + zero counters.
// ---------------------------------------------------------------------------
__global__ void prep_kernel(const float* __restrict__ P,
                            const float* __restrict__ Lab,
                            const int*   __restrict__ labels,
                            float* __restrict__ s_t,
                            int*   __restrict__ counts) {
    int gwave = (blockIdx.x * blockDim.x + threadIdx.x) >> 6;
    int lane  = threadIdx.x & 63;
    if (gwave >= B_ROWS) return;
    int t = labels[gwave];
    const float4* p4 = (const float4*)(P + (size_t)gwave * D_DIM);
    const float4* l4 = (const float4*)(Lab + (size_t)t * D_DIM);
    float4 a = p4[lane];
    float4 b = l4[lane];
    float sum = 0.f;
    sum += (float)(__bf16)a.x * (float)(__bf16)b.x;
    sum += (float)(__bf16)a.y * (float)(__bf16)b.y;
    sum += (float)(__bf16)a.z * (float)(__bf16)b.z;
    sum += (float)(__bf16)a.w * (float)(__bf16)b.w;
    #pragma unroll
    for (int m = 1; m < 64; m <<= 1) sum += __shfl_xor(sum, m, 64);
    if (lane == 0) {
        s_t[gwave]    = sum;
        counts[gwave] = 0;
    }
}

// ---------------------------------------------------------------------------
// Kernel 2 (v5): barrier-free, LDS-free streaming count GEMM.
// Block 256 thr = 4 waves: (wm in {0,1}) x (sp in {0,1}).
// Each wave: 64 stationary A rows in regs (af[4][8] = 128 VGPR) x full K=256;
// streams its strip's labels 16 at a time directly global->reg:
// per kb one global_load_dwordx4 (lane (quad,cc) reads Lb[n=cc][kb*32+quad*8],
// exactly the 16x16x32 B-operand layout). Depth-1 rolling prefetch: frag for
// step s+1 loaded immediately after frag s is consumed (~1 step lead >= L2
// latency). No __syncthreads anywhere; waves drift freely.
// wm-paired waves share a strip -> second wave L1-hits the same B lines.
// ---------------------------------------------------------------------------
__global__ __launch_bounds__(256, 2)
void count_kernel_v5(const __hip_bfloat16* __restrict__ Pb,
                     const __hip_bfloat16* __restrict__ Lb,
                     const int*   __restrict__ labels,
                     const float* __restrict__ s_t,
                     int* __restrict__ counts) {
    const int tid  = threadIdx.x;
    const int wave = tid >> 6;           // 0..3
    const int lane = tid & 63;
    const int wm   = wave >> 1;          // 0..1
    const int sp   = wave & 1;           // 0..1
    const int quad = lane >> 4;          // 0..3
    const int cc   = lane & 15;          // 0..15

    const int Mbase = blockIdx.y * 128 + wm * 64;
    const int sigma = blockIdx.x * 4 + blockIdx.z * 2 + sp;   // 0..63
    const int s0 = (sigma * NSTEP) >> 6;
    const int s1 = ((sigma + 1) * NSTEP) >> 6;

    // ---- stationary A fragments: 64 rows x K=256 ----
    bf16x8 af[4][8];
    #pragma unroll
    for (int mi = 0; mi < 4; ++mi) {
        const __bf16* ap = (const __bf16*)Pb +
            (size_t)(Mbase + mi * 16 + cc) * D_DIM + quad * 8;
        #pragma unroll
        for (int kb = 0; kb < 8; ++kb)
            af[mi][kb] = *(const bf16x8*)(ap + kb * 32);
    }

    // ---- per-row threshold / label ----
    float sr[4][4];
    int   tr[4][4];
    #pragma unroll
    for (int mi = 0; mi < 4; ++mi)
        #pragma unroll
        for (int r = 0; r < 4; ++r) {
            int row = Mbase + mi * 16 + quad * 4 + r;
            sr[mi][r] = s_t[row];
            tr[mi][r] = labels[row];
        }

    int cnt[4][4] = {};

    // per-lane B gather pointer: row = s*16 + cc, k-bytes = quad*16 (+kb*64)
    const char* pf = (const char*)Lb +
        (size_t)(s0 * 16 + cc) * (D_DIM * 2) + quad * 16;

    // prime step s0
    uint4 breg[8];
    #pragma unroll
    for (int kb = 0; kb < 8; ++kb)
        breg[kb] = *(const uint4*)(pf + kb * 64);
    pf += 16 * (D_DIM * 2);

    for (int s = s0; s < s1; ++s) {
        f32x4 acc[4] = {};
        #pragma unroll
        for (int kb = 0; kb < 8; ++kb) {
            bf16x8 bv = *(const bf16x8*)&breg[kb];
            #pragma unroll
            for (int mi = 0; mi < 4; ++mi)
                acc[mi] = __builtin_amdgcn_mfma_f32_16x16x32_bf16(
                    af[mi][kb], bv, acc[mi], 0, 0, 0);
            // rolling depth-1 prefetch of step s+1 (rows stay < L_PAD)
            breg[kb] = *(const uint4*)(pf + kb * 64);
        }
        pf += 16 * (D_DIM * 2);

        int n = s * 16 + cc;
        #pragma unroll
        for (int mi = 0; mi < 4; ++mi)
            #pragma unroll
            for (int r = 0; r < 4; ++r) {
                float sv = acc[mi][r];
                bool beat = (n != tr[mi][r]) &&
                            (sv > sr[mi][r] ||
                             (sv == sr[mi][r] && n < tr[mi][r]));
                cnt[mi][r] += beat ? 1 : 0;
            }
    }

    // ---- reduce over the 16 cc lanes, one atomic per (quad, mi, r) ----
    #pragma unroll
    for (int mi = 0; mi < 4; ++mi)
        #pragma unroll
        for (int r = 0; r < 4; ++r) {
            int v = cnt[mi][r];
            v += __shfl_xor(v, 1, 64);
            v += __shfl_xor(v, 2, 64);
            v += __shfl_xor(v, 4, 64);
            v += __shfl_xor(v, 8, 64);
            if (cc == 0) {
                int row = Mbase + mi * 16 + quad * 4 + r;
                atomicAdd(&counts[row], v);
            }
        }
}

// ---------------------------------------------------------------------------
// Kernel 2 (fallback, R1 path) — only if ws too small for bf16 copies.
// ---------------------------------------------------------------------------
#define FBM 128
#define FBN 128
#define FBK 32
#define KPAD 40

__global__ __launch_bounds__(256)
void count_kernel_slow(const float* __restrict__ P,
                       const float* __restrict__ Lab,
                       const int*   __restrict__ labels,
                       const float* __restrict__ s_t,
                       int* __restrict__ counts) {
    __shared__ __align__(16) __bf16 As[FBM][KPAD];
    __shared__ __align__(16) __bf16 Bs[FBN][KPAD];

    const int Nbase = blockIdx.x * FBN;
    const int Mbase = blockIdx.y * FBM;
    const int tid  = threadIdx.x;
    const int lane = tid & 63;
    const int wave = tid >> 6;
    const int wm = wave >> 1;
    const int wn = wave & 1;
    const int quad = lane >> 4;
    const int c    = lane & 15;

    const int srow  = tid >> 1;
    const int skoff = (tid & 1) * 16;
    const int brow_g = min(Nbase + srow, L_LABELS - 1);

    f32x4 acc[4][4] = {};

    for (int Kb = 0; Kb < D_DIM; Kb += FBK) {
        const float* gA = P   + (size_t)(Mbase + srow) * D_DIM + Kb + skoff;
        const float* gB = Lab + (size_t)brow_g        * D_DIM + Kb + skoff;
        #pragma unroll
        for (int i = 0; i < 4; ++i) {
            float4 va = *(const float4*)(gA + i * 4);
            float4 vb = *(const float4*)(gB + i * 4);
            *(bf16x4*)&As[srow][skoff + i * 4] =
                (bf16x4){(__bf16)va.x, (__bf16)va.y, (__bf16)va.z, (__bf16)va.w};
            *(bf16x4*)&Bs[srow][skoff + i * 4] =
                (bf16x4){(__bf16)vb.x, (__bf16)vb.y, (__bf16)vb.z, (__bf16)vb.w};
        }
        __syncthreads();

        bf16x8 afr[4], bfr[4];
        #pragma unroll
        for (int mi = 0; mi < 4; ++mi)
            afr[mi] = *(const bf16x8*)&As[wm * 64 + mi * 16 + c][quad * 8];
        #pragma unroll
        for (int ni = 0; ni < 4; ++ni)
            bfr[ni] = *(const bf16x8*)&Bs[wn * 64 + ni * 16 + c][quad * 8];

        #pragma unroll
        for (int mi = 0; mi < 4; ++mi)
            #pragma unroll
            for (int ni = 0; ni < 4; ++ni)
                acc[mi][ni] = __builtin_amdgcn_mfma_f32_16x16x32_bf16(
                    afr[mi], bfr[ni], acc[mi][ni], 0, 0, 0);
        __syncthreads();
    }

    #pragma unroll
    for (int mi = 0; mi < 4; ++mi) {
        int rowb = Mbase + wm * 64 + mi * 16 + quad * 4;
        #pragma unroll
        for (int r = 0; r < 4; ++r) {
            int   row = rowb + r;
            float st  = s_t[row];
            int   t   = labels[row];
            int   cnt = 0;
            #pragma unroll
            for (int ni = 0; ni < 4; ++ni) {
                int   n = Nbase + wn * 64 + ni * 16 + c;
                float s = acc[mi][ni][r];
                bool beat = (n < L_LABELS) && (n != t) &&
                            (s > st || (s == st && n < t));
                cnt += beat ? 1 : 0;
            }
            cnt += __shfl_xor(cnt, 1, 64);
            cnt += __shfl_xor(cnt, 2, 64);
            cnt += __shfl_xor(cnt, 4, 64);
            cnt += __shfl_xor(cnt, 8, 64);
            if (c == 0 && cnt) atomicAdd(&counts[row], cnt);
        }
    }
}

// ---------------------------------------------------------------------------
// Kernel 3: accuracy = mean(counts[b] < TOPK)
// ---------------------------------------------------------------------------
__global__ void finalize_kernel(const int* __restrict__ counts,
                                float* __restrict__ out) {
    __shared__ int sdata[4];
    int tid = threadIdx.x;
    int local = 0;
    for (int i = tid; i < B_ROWS; i += 256)
        local += (counts[i] < TOPK) ? 1 : 0;
    #pragma unroll
    for (int m = 1; m < 64; m <<= 1) local += __shfl_xor(local, m, 64);
    if ((tid & 63) == 0) sdata[tid >> 6] = local;
    __syncthreads();
    if (tid == 0)
        out[0] = (float)(sdata[0] + sdata[1] + sdata[2] + sdata[3]) /
                 (float)B_ROWS;
}

extern "C" void kernel_launch(void* const* d_in, const int* in_sizes, int n_in,
                              void* d_out, int out_size, void* d_ws, size_t ws_size,
                              hipStream_t stream) {
    const float* P      = (const float*)d_in[0];
    const float* Lab    = (const float*)d_in[1];
    const int*   labels = (const int*)d_in[2];
    float* out = (float*)d_out;

    float* s_t    = (float*)d_ws;
    int*   counts = (int*)((char*)d_ws + 16384);

    prep_kernel<<<dim3(B_ROWS / 4), 256, 0, stream>>>(P, Lab, labels, s_t, counts);

    const size_t pb_off = 32768;
    const size_t lb_off = pb_off + (size_t)B_ROWS * D_DIM * 2;  // 2 MB
    const size_t need   = lb_off + (size_t)L_PAD * D_DIM * 2;   // ~51 MB

    if (ws_size >= need) {
        __hip_bfloat16* Pb = (__hip_bfloat16*)((char*)d_ws + pb_off);
        __hip_bfloat16* Lb = (__hip_bfloat16*)((char*)d_ws + lb_off);
        convertP_kernel<<<dim3((B_ROWS * D_DIM) / 2048), 256, 0, stream>>>(P, Pb);
        convertL_kernel<<<dim3(((size_t)L_PAD * D_DIM) / 2048), 256, 0, stream>>>(Lab, Lb);
        // grid: 16 label-groups (XCD round-robin) x 32 M-tiles x 2
        count_kernel_v5<<<dim3(16, B_ROWS / 128, 2), 256, 0, stream>>>(
            Pb, Lb, labels, s_t, counts);
    } else {
        dim3 grid((L_LABELS + FBN - 1) / FBN, B_ROWS / FBM);
        count_kernel_slow<<<grid, 256, 0, stream>>>(P, Lab, labels, s_t, counts);
    }

    finalize_kernel<<<1, 256, 0, stream>>>(counts, out);
}